// Round 3
// baseline (378.069 us; speedup 1.0000x reference)
//
#include <hip/hip_runtime.h>
#include <hip/hip_bf16.h>

// ScaledDotProdAttn (no softmax): attn = (q@k^T)/8 ; out = attn@v
// B=32, SQ=SK=2048, D=64, fp32 in/out. d_out = [out (32*2048*64)] ++ [attn (32*2048*2048)]
// R2: R1 minus the sched_barrier(0) scheduler pins (m141 failure mode);
//     LOADT(kt+1) hoisted to top of S-phase so global loads span two phases.

typedef __attribute__((ext_vector_type(4))) float  f32x4;
typedef __attribute__((ext_vector_type(8))) short  s16x8;

#define NB    32
#define SQL   2048
#define SKL   2048
#define DD    64
#define QBLK  128
#define KBLK  128
#define NTILES (SKL / KBLK)

// LDS layout (64 KB -> 2 blocks/CU):
//   [0      ,16384) K tile   : 128 rows(key) x 64 bf16, stride 128 B, sw128
//   [16384  ,32768) V^T tile : 64 rows(d)   x 128 bf16, stride 256 B, sw256
//   [32768  ,65536) S tile   : 128 rows(q)  x 128 bf16, stride 256 B, sw256
#define KS_OFF 0
#define VT_OFF 16384
#define SS_OFF 32768

__device__ __forceinline__ unsigned short f2bf(float f) {
    union { float f; unsigned u; } x; x.f = f;
    unsigned r = x.u + 0x7FFFu + ((x.u >> 16) & 1u);   // RNE
    return (unsigned short)(r >> 16);
}

// XOR swizzles: touch byte-addr bits 4..6 only (16B-aligned stays aligned).
__device__ __forceinline__ unsigned sw128(unsigned row, unsigned bc) {
    return row * 128u + (bc ^ ((row & 7u) << 4));
}
__device__ __forceinline__ unsigned sw256(unsigned row, unsigned bc) {
    return row * 256u + (bc ^ ((((row >> 3) ^ row) & 7u) << 4));
}

// Raw workgroup barrier: drain LDS ops only; global loads/stores stay in
// flight across it (compiler still inserts counted vmcnt before any register
// USE of a load). Memory clobbers order all memory ops across the barrier;
// NO sched_barrier(0) — let the machine scheduler interleave freely.
__device__ __forceinline__ void bar_lds() {
    asm volatile("s_waitcnt lgkmcnt(0)" ::: "memory");
    __builtin_amdgcn_s_barrier();
    asm volatile("" ::: "memory");
}

__global__ __launch_bounds__(256, 2)
void sdpa_fused(const float* __restrict__ qg, const float* __restrict__ kg,
                const float* __restrict__ vg, float* __restrict__ og,
                float* __restrict__ ag) {
    __shared__ __align__(16) char smem[65536];

    const unsigned tid  = threadIdx.x;
    const unsigned wid  = tid >> 6;
    const unsigned lane = tid & 63u;
    const unsigned l15  = lane & 15u;
    const unsigned l4   = lane >> 4;        // 0..3
    const unsigned b    = blockIdx.x >> 4;
    const unsigned qt   = blockIdx.x & 15u;
    const unsigned qbase = qt * QBLK;
    const unsigned wr = wid >> 1, wc = wid & 1u;   // 2x2 wave grid for S

    const unsigned r0  = tid >> 3, c8 = tid & 7u;   // K staging map
    const unsigned t16 = tid >> 4, c4 = tid & 15u;  // V staging map

    // ---- stage Q (prescaled by 1/8) into SS region, sw128 layout ----
    {
        const float* src = qg + (size_t)b * SQL * DD + (size_t)qbase * DD;
        #pragma unroll
        for (int p = 0; p < 4; ++p) {
            unsigned row = p * 32 + r0;
            const f32x4* s = (const f32x4*)(src + row * DD + c8 * 8);
            f32x4 f0 = s[0], f1 = s[1];
            s16x8 h;
            #pragma unroll
            for (int j = 0; j < 4; ++j) {
                h[j]     = (short)f2bf(f0[j] * 0.125f);
                h[j + 4] = (short)f2bf(f1[j] * 0.125f);
            }
            *(s16x8*)(smem + SS_OFF + sw128(row, c8 * 16)) = h;
        }
    }
    bar_lds();

    // Q fragments are loop-invariant: hold in registers for the whole kernel.
    s16x8 aq[4][2];
    #pragma unroll
    for (int m = 0; m < 4; ++m)
        #pragma unroll
        for (int ks = 0; ks < 2; ++ks)
            aq[m][ks] = *(const s16x8*)(smem + SS_OFF +
                        sw128(wr * 64 + m * 16 + l15, ks * 64 + l4 * 16));

    f32x4 acc_o[2][4];
    #pragma unroll
    for (int m = 0; m < 2; ++m)
        #pragma unroll
        for (int n = 0; n < 4; ++n)
            acc_o[m][n] = (f32x4){0.f, 0.f, 0.f, 0.f};

    const float* kbat = kg + (size_t)b * SKL * DD;
    const float* vbat = vg + (size_t)b * SKL * DD;

    // register prefetch buffers (fp32, converted at STAGE time so the vmcnt
    // wait lands ~two phases after issue)
    f32x4 kbuf[4][2], vbuf[4][2];

    auto LOADT = [&](int kt) {
        const float* ksrc = kbat + (size_t)kt * KBLK * DD;
        const float* vsrc = vbat + (size_t)kt * KBLK * DD;
        #pragma unroll
        for (int p = 0; p < 4; ++p) {
            unsigned krow = p * 32 + r0;
            const f32x4* s = (const f32x4*)(ksrc + krow * DD + c8 * 8);
            kbuf[p][0] = s[0];
            kbuf[p][1] = s[1];
            unsigned vrow = p * 32 + 2 * t16;
            vbuf[p][0] = *(const f32x4*)(vsrc + vrow * DD + c4 * 4);
            vbuf[p][1] = *(const f32x4*)(vsrc + (vrow + 1) * DD + c4 * 4);
        }
    };

    auto STAGE = [&]() {
        #pragma unroll
        for (int p = 0; p < 4; ++p) {
            unsigned krow = p * 32 + r0;
            f32x4 f0 = kbuf[p][0], f1 = kbuf[p][1];
            s16x8 h;
            #pragma unroll
            for (int j = 0; j < 4; ++j) {
                h[j]     = (short)f2bf(f0[j]);
                h[j + 4] = (short)f2bf(f1[j]);
            }
            *(s16x8*)(smem + KS_OFF + sw128(krow, c8 * 16)) = h;

            unsigned vrow = p * 32 + 2 * t16;
            f32x4 g0 = vbuf[p][0], g1 = vbuf[p][1];
            #pragma unroll
            for (int j = 0; j < 4; ++j) {
                unsigned d = c4 * 4 + (unsigned)j;
                unsigned pack = (unsigned)f2bf(g0[j]) | ((unsigned)f2bf(g1[j]) << 16);
                *(unsigned*)(smem + VT_OFF + sw256(d, vrow * 2)) = pack;
            }
        }
    };

    LOADT(0);

    for (int kt = 0; kt < NTILES; ++kt) {
        STAGE();                          // consumes kbuf/vbuf (counted vmcnt here)
        bar_lds();

        // issue next tile's loads FIRST: in flight across S + PV phases
        if (kt + 1 < NTILES) LOADT(kt + 1);

        // ---- S = Q * K^T (scale folded into Q) ----
        f32x4 acc[4][4];
        #pragma unroll
        for (int m = 0; m < 4; ++m)
            #pragma unroll
            for (int n = 0; n < 4; ++n)
                acc[m][n] = (f32x4){0.f, 0.f, 0.f, 0.f};

        #pragma unroll
        for (int ks = 0; ks < 2; ++ks) {
            s16x8 bk[4];
            #pragma unroll
            for (int n = 0; n < 4; ++n)
                bk[n] = *(const s16x8*)(smem + KS_OFF +
                        sw128(wc * 64 + n * 16 + l15, ks * 64 + l4 * 16));
            #pragma unroll
            for (int m = 0; m < 4; ++m)
                #pragma unroll
                for (int n = 0; n < 4; ++n)
                    acc[m][n] = __builtin_amdgcn_mfma_f32_16x16x32_bf16(
                                    aq[m][ks], bk[n], acc[m][n], 0, 0, 0);
        }

        // ---- S->bf16 into LDS, then attn fp32 stores (stay in flight) ----
        #pragma unroll
        for (int m = 0; m < 4; ++m)
            #pragma unroll
            for (int n = 0; n < 4; ++n)
                #pragma unroll
                for (int i = 0; i < 4; ++i) {
                    unsigned ql = wr * 64 + m * 16 + l4 * 4 + (unsigned)i;
                    unsigned kl = wc * 64 + n * 16 + l15;
                    *(unsigned short*)(smem + SS_OFF + sw256(ql, kl * 2)) =
                        f2bf(acc[m][n][i]);
                }

        float* ap = ag + (size_t)b * SQL * SKL
                       + (size_t)(qbase + wr * 64 + l4 * 4) * SKL
                       + (size_t)kt * KBLK + wc * 64 + l15;
        #pragma unroll
        for (int m = 0; m < 4; ++m)
            #pragma unroll
            for (int i = 0; i < 4; ++i) {
                float* rowp = ap + (size_t)(m * 16 + i) * SKL;
                #pragma unroll
                for (int n = 0; n < 4; ++n)
                    __builtin_nontemporal_store(acc[m][n][i], rowp + n * 16);
            }
        bar_lds();

        // ---- O += S * V ---- (each wave: 32 q-rows x 64 d)
        #pragma unroll
        for (int ks = 0; ks < 4; ++ks) {
            s16x8 sa0 = *(const s16x8*)(smem + SS_OFF +
                        sw256(wid * 32 + l15,      ks * 64 + l4 * 16));
            s16x8 sa1 = *(const s16x8*)(smem + SS_OFF +
                        sw256(wid * 32 + 16 + l15, ks * 64 + l4 * 16));
            #pragma unroll
            for (int n = 0; n < 4; ++n) {
                s16x8 vb = *(const s16x8*)(smem + VT_OFF +
                           sw256(n * 16 + l15, ks * 64 + l4 * 16));
                acc_o[0][n] = __builtin_amdgcn_mfma_f32_16x16x32_bf16(sa0, vb, acc_o[0][n], 0, 0, 0);
                acc_o[1][n] = __builtin_amdgcn_mfma_f32_16x16x32_bf16(sa1, vb, acc_o[1][n], 0, 0, 0);
            }
        }
        bar_lds();
    }

    // ---- write O ----
    float* op = og + (size_t)b * SQL * DD
                   + (size_t)(qbase + wid * 32 + l4 * 4) * DD + l15;
    #pragma unroll
    for (int m = 0; m < 2; ++m)
        #pragma unroll
        for (int n = 0; n < 4; ++n)
            #pragma unroll
            for (int i = 0; i < 4; ++i)
                __builtin_nontemporal_store(acc_o[m][n][i], op + (m * 16 + i) * DD + n * 16);
}

extern "C" void kernel_launch(void* const* d_in, const int* in_sizes, int n_in,
                              void* d_out, int out_size, void* d_ws, size_t ws_size,
                              hipStream_t stream) {
    const float* q = (const float*)d_in[0];
    const float* k = (const float*)d_in[1];
    const float* v = (const float*)d_in[2];
    float* outp  = (float*)d_out;                      // [32][2048][64]
    float* attnp = outp + (size_t)NB * SQL * DD;       // [32][2048][2048]
    sdpa_fused<<<dim3(NB * (SQL / QBLK)), dim3(256), 0, stream>>>(q, k, v, outp, attnp);
}

// Round 4
// 273.083 us; speedup vs baseline: 1.3844x; 1.3844x over previous
//
#include <hip/hip_runtime.h>
#include <hip/hip_bf16.h>

// ScaledDotProdAttn (no softmax): attn = (q@k^T)/8 ; out = attn@v
// B=32, SQ=SK=2048, D=64, fp32 in/out. d_out = [out (32*2048*64)] ++ [attn (32*2048*2048)]
// R4: back to R0's proven structure (__syncthreads, in-phase staging), plus:
//  - KBLK 128->64: LDS 32 KB -> 4 blocks/CU (16 waves/CU) for stall overlap
//  - XCD-aware block mapping: one batch's 16 Q-blocks share one XCD's L2
//  - dense per-instruction global loads; V^T swizzle fixed for its write axis

typedef __attribute__((ext_vector_type(4))) float  f32x4;
typedef __attribute__((ext_vector_type(8))) short  s16x8;
typedef __attribute__((ext_vector_type(4))) short  s16x4;

#define NB    32
#define SQL   2048
#define SKL   2048
#define DD    64
#define QBLK  128
#define KBLK  64
#define NTILES (SKL / KBLK)

// LDS layout (32 KB -> 4 blocks/CU):
//   [0    , 8192) K tile   : 64 rows(key) x 64 bf16, stride 128 B, swA
//   [8192 ,16384) V^T tile : 64 rows(d)   x 64 bf16, stride 128 B, swB
//   [16384,32768) S tile   : 128 rows(q)  x 64 bf16, stride 128 B, swA
//   (Q staged once into S region with swA, read to regs, region then reused)
#define KS_OFF 0
#define VT_OFF 8192
#define SS_OFF 16384

__device__ __forceinline__ unsigned short f2bf(float f) {
    union { float f; unsigned u; } x; x.f = f;
    unsigned r = x.u + 0x7FFFu + ((x.u >> 16) & 1u);   // RNE
    return (unsigned short)(r >> 16);
}

// swA: for tiles read with row = l15 (row&7 varies per lane).
__device__ __forceinline__ unsigned swA(unsigned row, unsigned bc) {
    return row * 128u + (bc ^ ((row & 7u) << 4));
}
// swB: for V^T, whose staging writes have (row&7) constant per instruction
// but (row>>3) varying — fold both into the XOR.
__device__ __forceinline__ unsigned swB(unsigned row, unsigned bc) {
    return row * 128u + (bc ^ ((((row >> 3) ^ row) & 7u) << 4));
}

__global__ __launch_bounds__(256, 4)
void sdpa_fused(const float* __restrict__ qg, const float* __restrict__ kg,
                const float* __restrict__ vg, float* __restrict__ og,
                float* __restrict__ ag) {
    __shared__ __align__(16) char smem[32768];

    const unsigned tid  = threadIdx.x;
    const unsigned wid  = tid >> 6;
    const unsigned lane = tid & 63u;
    const unsigned l15  = lane & 15u;
    const unsigned l4   = lane >> 4;        // 0..3

    // XCD-aware mapping: 512 blocks, blockIdx.x % 8 = XCD (round-robin).
    // XCD x owns batches 4x..4x+3; the 16 Q-blocks of a batch co-reside.
    const unsigned xcd = blockIdx.x & 7u;
    const unsigned loc = blockIdx.x >> 3;        // 0..63
    const unsigned b   = xcd * 4u + (loc >> 4);  // batch
    const unsigned qt  = loc & 15u;              // q-tile in batch
    const unsigned qbase = qt * QBLK;
    const unsigned wr = wid >> 1, wc = wid & 1u; // 2x2 wave grid for S

    const unsigned r16 = tid >> 4, c16 = tid & 15u;  // dense K/Q staging map
    const unsigned t8  = tid >> 3, c8  = tid & 7u;   // V staging map

    // ---- stage Q (prescaled by 1/8) into SS region, swA layout ----
    {
        const float* src = qg + (size_t)b * SQL * DD + (size_t)qbase * DD;
        #pragma unroll
        for (int j = 0; j < 8; ++j) {
            unsigned row = r16 + j * 16;
            f32x4 f = *(const f32x4*)(src + row * DD + c16 * 4);
            s16x4 h;
            #pragma unroll
            for (int e = 0; e < 4; ++e) h[e] = (short)f2bf(f[e] * 0.125f);
            *(s16x4*)(smem + SS_OFF + swA(row, c16 * 8)) = h;
        }
    }
    __syncthreads();

    // Q fragments are loop-invariant: hold in registers for the whole kernel.
    s16x8 aq[4][2];
    #pragma unroll
    for (int m = 0; m < 4; ++m)
        #pragma unroll
        for (int ks = 0; ks < 2; ++ks)
            aq[m][ks] = *(const s16x8*)(smem + SS_OFF +
                        swA(wr * 64 + m * 16 + l15, ks * 64 + l4 * 16));

    f32x4 acc_o[2][4];
    #pragma unroll
    for (int m = 0; m < 2; ++m)
        #pragma unroll
        for (int n = 0; n < 4; ++n)
            acc_o[m][n] = (f32x4){0.f, 0.f, 0.f, 0.f};

    const float* kbat = kg + (size_t)b * SKL * DD;
    const float* vbat = vg + (size_t)b * SKL * DD;
    __syncthreads();   // Q reads to regs done before tile 0 overwrites SS

    for (int kt = 0; kt < NTILES; ++kt) {
        // ---- stage K tile (swA) and V^T tile (swB) ----
        {
            const float* ksrc = kbat + (size_t)kt * KBLK * DD;
            const float* vsrc = vbat + (size_t)kt * KBLK * DD;
            #pragma unroll
            for (int j = 0; j < 4; ++j) {
                unsigned row = r16 + j * 16;
                f32x4 f = *(const f32x4*)(ksrc + row * DD + c16 * 4);
                s16x4 h;
                #pragma unroll
                for (int e = 0; e < 4; ++e) h[e] = (short)f2bf(f[e]);
                *(s16x4*)(smem + KS_OFF + swA(row, c16 * 8)) = h;
            }
            // V: keys 2*t8, 2*t8+1 ; d-range c8*8..+7 ; pack 2 keys per u32
            f32x4 v00 = *(const f32x4*)(vsrc + (2 * t8) * DD + c8 * 8);
            f32x4 v01 = *(const f32x4*)(vsrc + (2 * t8) * DD + c8 * 8 + 4);
            f32x4 v10 = *(const f32x4*)(vsrc + (2 * t8 + 1) * DD + c8 * 8);
            f32x4 v11 = *(const f32x4*)(vsrc + (2 * t8 + 1) * DD + c8 * 8 + 4);
            #pragma unroll
            for (int j = 0; j < 4; ++j) {
                unsigned d0 = c8 * 8 + (unsigned)j;
                unsigned d1 = d0 + 4;
                unsigned p0 = (unsigned)f2bf(v00[j]) | ((unsigned)f2bf(v10[j]) << 16);
                unsigned p1 = (unsigned)f2bf(v01[j]) | ((unsigned)f2bf(v11[j]) << 16);
                *(unsigned*)(smem + VT_OFF + swB(d0, t8 * 4)) = p0;
                *(unsigned*)(smem + VT_OFF + swB(d1, t8 * 4)) = p1;
            }
        }
        __syncthreads();

        // ---- S = Q * K^T (scale folded into Q); wave: 64 q x 32 keys ----
        f32x4 acc[4][2];
        #pragma unroll
        for (int m = 0; m < 4; ++m)
            #pragma unroll
            for (int n = 0; n < 2; ++n)
                acc[m][n] = (f32x4){0.f, 0.f, 0.f, 0.f};

        #pragma unroll
        for (int ks = 0; ks < 2; ++ks) {
            s16x8 bk[2];
            #pragma unroll
            for (int n = 0; n < 2; ++n)
                bk[n] = *(const s16x8*)(smem + KS_OFF +
                        swA(wc * 32 + n * 16 + l15, ks * 64 + l4 * 16));
            #pragma unroll
            for (int m = 0; m < 4; ++m)
                #pragma unroll
                for (int n = 0; n < 2; ++n)
                    acc[m][n] = __builtin_amdgcn_mfma_f32_16x16x32_bf16(
                                    aq[m][ks], bk[n], acc[m][n], 0, 0, 0);
        }

        // ---- write attn (fp32, nontemporal) + S->bf16 into LDS ----
        float* ap = ag + (size_t)b * SQL * SKL
                       + (size_t)(qbase + wr * 64 + l4 * 4) * SKL
                       + (size_t)kt * KBLK + wc * 32 + l15;
        #pragma unroll
        for (int m = 0; m < 4; ++m)
            #pragma unroll
            for (int n = 0; n < 2; ++n)
                #pragma unroll
                for (int i = 0; i < 4; ++i) {
                    float val = acc[m][n][i];
                    __builtin_nontemporal_store(val, ap + (size_t)(m * 16 + i) * SKL + n * 16);
                    unsigned ql = wr * 64 + m * 16 + l4 * 4 + (unsigned)i;
                    unsigned kl = wc * 32 + n * 16 + l15;
                    *(unsigned short*)(smem + SS_OFF + swA(ql, kl * 2)) = f2bf(val);
                }
        __syncthreads();

        // ---- O += S * V ---- (each wave: 32 q-rows x 64 d)
        #pragma unroll
        for (int ks = 0; ks < 2; ++ks) {
            s16x8 sa0 = *(const s16x8*)(smem + SS_OFF +
                        swA(wid * 32 + l15,      ks * 64 + l4 * 16));
            s16x8 sa1 = *(const s16x8*)(smem + SS_OFF +
                        swA(wid * 32 + 16 + l15, ks * 64 + l4 * 16));
            #pragma unroll
            for (int n = 0; n < 4; ++n) {
                s16x8 vb = *(const s16x8*)(smem + VT_OFF +
                           swB(n * 16 + l15, ks * 64 + l4 * 16));
                acc_o[0][n] = __builtin_amdgcn_mfma_f32_16x16x32_bf16(sa0, vb, acc_o[0][n], 0, 0, 0);
                acc_o[1][n] = __builtin_amdgcn_mfma_f32_16x16x32_bf16(sa1, vb, acc_o[1][n], 0, 0, 0);
            }
        }
        __syncthreads();
    }

    // ---- write O ----
    float* op = og + (size_t)b * SQL * DD
                   + (size_t)(qbase + wid * 32 + l4 * 4) * DD + l15;
    #pragma unroll
    for (int m = 0; m < 2; ++m)
        #pragma unroll
        for (int n = 0; n < 4; ++n)
            #pragma unroll
            for (int i = 0; i < 4; ++i)
                __builtin_nontemporal_store(acc_o[m][n][i], op + (m * 16 + i) * DD + n * 16);
}

extern "C" void kernel_launch(void* const* d_in, const int* in_sizes, int n_in,
                              void* d_out, int out_size, void* d_ws, size_t ws_size,
                              hipStream_t stream) {
    const float* q = (const float*)d_in[0];
    const float* k = (const float*)d_in[1];
    const float* v = (const float*)d_in[2];
    float* outp  = (float*)d_out;                      // [32][2048][64]
    float* attnp = outp + (size_t)NB * SQL * DD;       // [32][2048][2048]
    sdpa_fused<<<dim3(NB * (SQL / QBLK)), dim3(256), 0, stream>>>(q, k, v, outp, attnp);
}

// Round 5
// 127.435 us; speedup vs baseline: 2.9668x; 2.1429x over previous
//
#include <hip/hip_runtime.h>
#include <hip/hip_bf16.h>

// ScaledDotProdAttn (no softmax): attn = (q@k^T)/8 ; out = attn@v
// B=32, SQ=SK=2048, D=64, fp32 in/out. d_out = [out] ++ [attn]
// R5: 8-wave blocks, wave-private S (no mid-tile barrier), double-buffered
//     K/V (one __syncthreads per tile), attn stored via LDS readback as
//     8x128B segments, Q direct-to-register, XCD-aware block mapping.

typedef __attribute__((ext_vector_type(4))) float        f32x4;
typedef __attribute__((ext_vector_type(8))) short        s16x8;
typedef __attribute__((ext_vector_type(2))) unsigned int u32x2;
typedef __attribute__((ext_vector_type(4))) unsigned int u32x4;

#define NB    32
#define SQL   2048
#define SKL   2048
#define DD    64
#define QBLK  128
#define KBLK  64
#define NTILES (SKL / KBLK)

// LDS (48 KB -> 2 blocks/CU with 512-thread blocks = 16 waves/CU):
//   [0    ,16384) K dbuf : 2 x (64 keys x 64 bf16), row stride 128 B
//   [16384,32768) V^T dbuf: 2 x (64 d x 64 keys bf16 packed), stride 128 B
//   [32768,49152) S priv : 8 waves x (16 q x 64 k bf16), stride 128 B
#define KOFF 0
#define VOFF 16384
#define SOFF 32768

__device__ __forceinline__ unsigned short f2bf(float f) {
    union { float f; unsigned u; } x; x.f = f;
    unsigned r = x.u + 0x7FFFu + ((x.u >> 16) & 1u);   // RNE
    return (unsigned short)(r >> 16);
}
// swizzles: XOR into byte-addr bits 4..6 (row stride 128 B everywhere)
__device__ __forceinline__ unsigned swzK(unsigned k) { return (k & 7u) << 4; }
__device__ __forceinline__ unsigned swzV(unsigned d) { return (d & 7u) << 4; }
__device__ __forceinline__ unsigned swzS(unsigned q) { return ((q + (q >> 3)) & 7u) << 4; }

__global__ __launch_bounds__(512, 4)
void sdpa_fused(const float* __restrict__ qg, const float* __restrict__ kg,
                const float* __restrict__ vg, float* __restrict__ og,
                float* __restrict__ ag) {
    __shared__ __align__(16) char smem[49152];

    const unsigned tid  = threadIdx.x;
    const unsigned wid  = tid >> 6;          // 0..7
    const unsigned lane = tid & 63u;
    const unsigned l15  = lane & 15u;
    const unsigned l4   = lane >> 4;         // 0..3

    // XCD-aware mapping (kept from R4: FETCH 417->43 MB win)
    const unsigned xcd = blockIdx.x & 7u;
    const unsigned loc = blockIdx.x >> 3;        // 0..63
    const unsigned b   = xcd * 4u + (loc >> 4);  // batch
    const unsigned qt  = loc & 15u;              // q-tile in batch
    const unsigned qbase = qt * QBLK;

    // staging maps (512 threads)
    const unsigned kr = tid >> 3, kc = tid & 7u;   // K: row 0..63, 32B chunk
    const unsigned vt = tid >> 4, vc = tid & 15u;  // V: key-pair 0..31, d-chunk

    // ---- Q -> A-fragments directly from global (scale folded in) ----
    s16x8 aq[2];
    {
        const float* qrow = qg + ((size_t)b * SQL + qbase + wid * 16 + l15) * DD;
        #pragma unroll
        for (int ks = 0; ks < 2; ++ks) {
            f32x4 f0 = *(const f32x4*)(qrow + ks * 32 + l4 * 8);
            f32x4 f1 = *(const f32x4*)(qrow + ks * 32 + l4 * 8 + 4);
            #pragma unroll
            for (int j = 0; j < 4; ++j) {
                aq[ks][j]     = (short)f2bf(f0[j] * 0.125f);
                aq[ks][j + 4] = (short)f2bf(f1[j] * 0.125f);
            }
        }
    }

    f32x4 acc_o[4];
    #pragma unroll
    for (int n = 0; n < 4; ++n) acc_o[n] = (f32x4){0.f, 0.f, 0.f, 0.f};

    const float* kbat = kg + (size_t)b * SKL * DD;
    const float* vbat = vg + (size_t)b * SKL * DD;

    auto stage = [&](int kt, int sel) {
        const float* ksrc = kbat + (size_t)kt * KBLK * DD;
        const float* vsrc = vbat + (size_t)kt * KBLK * DD;
        // K: 1 row x 32B fp32 per thread -> one b128 LDS write
        f32x4 k0 = *(const f32x4*)(ksrc + kr * DD + kc * 8);
        f32x4 k1 = *(const f32x4*)(ksrc + kr * DD + kc * 8 + 4);
        s16x8 h;
        #pragma unroll
        for (int j = 0; j < 4; ++j) {
            h[j]     = (short)f2bf(k0[j]);
            h[j + 4] = (short)f2bf(k1[j]);
        }
        *(s16x8*)(smem + KOFF + sel * 8192 + kr * 128 + ((kc * 16) ^ swzK(kr))) = h;
        // V^T: key-pair (2vt,2vt+1), d = vc*4..+3, packed 2 keys / u32
        f32x4 v0 = *(const f32x4*)(vsrc + (2 * vt) * DD + vc * 4);
        f32x4 v1 = *(const f32x4*)(vsrc + (2 * vt + 1) * DD + vc * 4);
        #pragma unroll
        for (int j = 0; j < 4; ++j) {
            unsigned d = vc * 4 + (unsigned)j;
            unsigned pack = (unsigned)f2bf(v0[j]) | ((unsigned)f2bf(v1[j]) << 16);
            *(unsigned*)(smem + VOFF + sel * 8192 + d * 128 + ((vt * 4) ^ swzV(d))) = pack;
        }
    };

    stage(0, 0);
    __syncthreads();

    char* sbase = smem + SOFF + wid * 2048;   // wave-private S: 16 x 128 B
    const unsigned rr = lane >> 3, cc = lane & 7u;  // attn readback map

    for (int kt = 0; kt < NTILES; ++kt) {
        const int cur = kt & 1;
        if (kt + 1 < NTILES) stage(kt + 1, cur ^ 1);

        // ---- S = Q @ K^T : wave's 16 q-rows x 64 keys ----
        const char* kb = smem + KOFF + cur * 8192;
        f32x4 acc[4];
        #pragma unroll
        for (int n = 0; n < 4; ++n) acc[n] = (f32x4){0.f, 0.f, 0.f, 0.f};
        #pragma unroll
        for (int ks = 0; ks < 2; ++ks)
            #pragma unroll
            for (int nk = 0; nk < 4; ++nk) {
                unsigned row = nk * 16 + l15;
                s16x8 bk = *(const s16x8*)(kb + row * 128 +
                            ((ks * 64 + l4 * 16) ^ swzK(row)));
                acc[nk] = __builtin_amdgcn_mfma_f32_16x16x32_bf16(
                              aq[ks], bk, acc[nk], 0, 0, 0);
            }

        // ---- S -> wave-private LDS (bf16); no barrier needed ----
        #pragma unroll
        for (int nk = 0; nk < 4; ++nk)
            #pragma unroll
            for (int i = 0; i < 4; ++i) {
                unsigned q = l4 * 4 + (unsigned)i;
                unsigned key = nk * 16 + l15;
                *(unsigned short*)(sbase + q * 128 + ((key * 2) ^ swzS(q))) =
                    f2bf(acc[nk][i]);
            }

        // ---- attn stores via readback: 8 lanes/row -> 128B segments ----
        {
            float* abase = ag + ((size_t)b * SQL + qbase + wid * 16) * SKL
                              + (size_t)kt * KBLK;
            #pragma unroll
            for (int h = 0; h < 4; ++h) {
                unsigned q  = (h & 1) * 8 + rr;
                unsigned k4 = (h >> 1) * 32 + cc * 4;
                u32x2 p = *(const u32x2*)(sbase + q * 128 + ((k4 * 2) ^ swzS(q)));
                u32x4 w;
                w[0] = p[0] << 16; w[1] = p[0] & 0xFFFF0000u;
                w[2] = p[1] << 16; w[3] = p[1] & 0xFFFF0000u;
                __builtin_nontemporal_store(w,
                    (u32x4*)(abase + (size_t)q * SKL + k4));
            }
        }

        // ---- O += S @ V ----
        const char* vb = smem + VOFF + cur * 8192;
        #pragma unroll
        for (int ks = 0; ks < 2; ++ks) {
            s16x8 sa = *(const s16x8*)(sbase + l15 * 128 +
                        ((ks * 64 + l4 * 16) ^ swzS(l15)));
            #pragma unroll
            for (int nd = 0; nd < 4; ++nd) {
                unsigned row = nd * 16 + l15;
                s16x8 vf = *(const s16x8*)(vb + row * 128 +
                            ((ks * 64 + l4 * 16) ^ swzV(row)));
                acc_o[nd] = __builtin_amdgcn_mfma_f32_16x16x32_bf16(
                                sa, vf, acc_o[nd], 0, 0, 0);
            }
        }

        __syncthreads();   // one barrier per tile (dbuf flip)
    }

    // ---- write O ----
    float* op = og + ((size_t)b * SQL + qbase + wid * 16 + l4 * 4) * DD + l15;
    #pragma unroll
    for (int nd = 0; nd < 4; ++nd)
        #pragma unroll
        for (int i = 0; i < 4; ++i)
            __builtin_nontemporal_store(acc_o[nd][i], op + (size_t)i * DD + nd * 16);
}

extern "C" void kernel_launch(void* const* d_in, const int* in_sizes, int n_in,
                              void* d_out, int out_size, void* d_ws, size_t ws_size,
                              hipStream_t stream) {
    const float* q = (const float*)d_in[0];
    const float* k = (const float*)d_in[1];
    const float* v = (const float*)d_in[2];
    float* outp  = (float*)d_out;                      // [32][2048][64]
    float* attnp = outp + (size_t)NB * SQL * DD;       // [32][2048][2048]
    sdpa_fused<<<dim3(NB * (SQL / QBLK)), dim3(512), 0, stream>>>(q, k, v, outp, attnp);
}